// Round 3
// baseline (635.785 us; speedup 1.0000x reference)
//
#include <hip/hip_runtime.h>

typedef __bf16 bf16x8 __attribute__((ext_vector_type(8)));
typedef __bf16 bf16x4 __attribute__((ext_vector_type(4)));
typedef __bf16 bf16x2 __attribute__((ext_vector_type(2)));
typedef float  f32x4  __attribute__((ext_vector_type(4)));
typedef int    i32x4  __attribute__((ext_vector_type(4)));

static constexpr int kS = 8192;
static constexpr int kD = 128;
static constexpr int kRowsPerTensor = 2 * 16 * kS;            // 262144
static constexpr int kFragElems = kD * kD;                    // 16384 bf16
static constexpr int kTileRows = 64;                          // rows per tile
static constexpr int kTilesPerBlock = 8;
static constexpr int kTilesPerTensor = kRowsPerTensor / kTileRows;  // 4096

// ---------------------------------------------------------------------------
// Kernel 1: build Householder product Q, column-parallel (one wave per column).
//   wsQA : Q in MFMA A-fragment order (A of swapped GEMM1; staged to LDS once)
//   wsQf : Q in MFMA B-fragment order (B of GEMM2; read from global, L1/L2-hot)
// ---------------------------------------------------------------------------
__global__ __launch_bounds__(1024) void rnrope_build_q(
    const float* __restrict__ vs,
    __bf16* __restrict__ wsQA,
    __bf16* __restrict__ wsQf) {
  __shared__ float vsh[64 * 128];
  const int tid = threadIdx.x;
  for (int i = tid; i < 2048; i += 1024)
    ((float4*)vsh)[i] = ((const float4*)vs)[i];
  __syncthreads();

  const int col  = blockIdx.x * 16 + (tid >> 6);  // 0..127 (grid = 8 blocks)
  const int lane = tid & 63;

  float qlo = (col == lane)      ? 1.0f : 0.0f;   // Q[lane][col]
  float qhi = (col == lane + 64) ? 1.0f : 0.0f;   // Q[lane+64][col]

  for (int r = 0; r < 64; ++r) {
    float vlo = vsh[r * 128 + lane];
    float vhi = vsh[r * 128 + lane + 64];
    float t0 = vlo * qlo + vhi * qhi;
    float t1 = vlo * vlo + vhi * vhi;
    #pragma unroll
    for (int off = 32; off > 0; off >>= 1) {
      t0 += __shfl_xor(t0, off);
      t1 += __shfl_xor(t1, off);
    }
    float sf = 2.0f / (t1 + 1e-8f) * t0;
    qlo -= sf * vlo;
    qhi -= sf * vhi;
  }

  // A-frag(Q): element Q[i][col], i = lane, lane+64
  {
    const int ks = col >> 5, qdc = (col >> 3) & 3, jj = col & 7;
    #pragma unroll
    for (int h = 0; h < 2; ++h) {
      int i = lane + h * 64;
      float val = h ? qhi : qlo;
      int mt = i >> 4, rl = i & 15;
      wsQA[((mt * 4 + ks) * 64 + qdc * 16 + rl) * 8 + jj] = (__bf16)val;
    }
  }
  // B-frag(Q): element Q[i][col] at B[k=i][n=col]
  {
    const int nt = col >> 4;
    const int nn = col & 15;
    #pragma unroll
    for (int h = 0; h < 2; ++h) {
      int i = lane + h * 64;
      float val = h ? qhi : qlo;
      int ks = i >> 5, qdc = (i >> 3) & 3, jj = i & 7;
      wsQf[((ks * 8 + nt) * 64 + qdc * 16 + nn) * 8 + jj] = (__bf16)val;
    }
  }
}

// lgkm-only barrier: does NOT drain vmcnt, so prefetch loads / stores stay in
// flight across it (unlike __syncthreads, which emits s_waitcnt vmcnt(0)).
__device__ __forceinline__ void lds_barrier() {
  asm volatile("s_waitcnt lgkmcnt(0)" ::: "memory");
  __builtin_amdgcn_s_barrier();
  asm volatile("" ::: "memory");
}

// ---------------------------------------------------------------------------
// Kernel 2: persistent software-pipelined. 1024 blocks x 8 tiles of 64 rows.
// 256 threads (4 waves, 16 rows/wave). LDS = Q A-frags (32KB, staged once)
// + one X-frag slot (16KB) -> 48KB -> 3 blocks/CU.
// Per tile t: barrier_A | cvt+ds_write regs(t) | issue loads(t+1) | barrier_B |
//             GEMM1 (LDS) -> RoPE (reg) -> bpermute crossbar -> GEMM2 -> stores.
// Loads for t+1 remain in flight across the whole compute of t (T14).
// ---------------------------------------------------------------------------
__global__ __launch_bounds__(256, 3) void rnrope_main(
    const float* __restrict__ qg, const float* __restrict__ kg,
    const __bf16* __restrict__ wsQA, const __bf16* __restrict__ wsQf,
    float* __restrict__ outg) {
  __shared__ __align__(16) __bf16 ldsQ[kFragElems];      // 32 KiB
  __shared__ __align__(16) __bf16 ldsX[kFragElems / 2];  // 16 KiB (64 rows)

  const int tid  = threadIdx.x;
  const int w    = tid >> 6;     // wave 0..3, owns rows (tile) + w*16 .. +15
  const int lane = tid & 63;
  const int qd   = lane >> 4;
  const int cc   = lane & 15;

  // stage Q A-frags once per block (coalesced 32KB copy)
  #pragma unroll
  for (int i = 0; i < 8; ++i)
    ((uint4*)ldsQ)[tid + i * 256] = ((const uint4*)wsQA)[tid + i * 256];

  const int g0 = blockIdx.x * kTilesPerBlock;

  float4 xr[8];
  // prologue: issue loads for first tile
  {
    const float* __restrict__ Xg = (g0 >> 12) ? kg : qg;
    const int row0 = (g0 & (kTilesPerTensor - 1)) * kTileRows;
    #pragma unroll
    for (int it = 0; it < 8; ++it) {
      int f = tid + it * 256;            // float4 index, 2048 total
      int mloc = f >> 5, q4 = f & 31;
      xr[it] = ((const float4*)(Xg + (size_t)(row0 + mloc) * kD))[q4];
    }
  }

  for (int tt = 0; tt < kTilesPerBlock; ++tt) {
    const int g      = g0 + tt;
    const int tensor = g >> 12;
    const int row0   = (g & (kTilesPerTensor - 1)) * kTileRows;
    float* __restrict__ Og =
        outg + (size_t)tensor * (size_t)kRowsPerTensor * kD + (size_t)row0 * kD;

    lds_barrier();   // A: all waves done reading ldsX(t-1); Q staged (1st iter)

    // cvt + write tile t into ldsX frag layout (auto counted-vmcnt on xr)
    #pragma unroll
    for (int it = 0; it < 8; ++it) {
      int f = tid + it * 256;
      int mloc = f >> 5, q4 = f & 31;
      int k0 = q4 * 4;
      int ks = k0 >> 5, qdc = (k0 >> 3) & 3, j = k0 & 7;
      int ww = mloc >> 4, m = mloc & 15;
      int idx = ((ww * 4 + ks) * 64 + qdc * 16 + m) * 8 + j;
      float4 x4 = xr[it];
      bf16x4 v;
      v[0] = (__bf16)x4.x; v[1] = (__bf16)x4.y; v[2] = (__bf16)x4.z; v[3] = (__bf16)x4.w;
      *(bf16x4*)(&ldsX[idx]) = v;
    }

    // issue loads for tile t+1 (fly across the whole compute phase)
    if (tt + 1 < kTilesPerBlock) {
      const int g2 = g + 1;
      const float* __restrict__ Xg2 = (g2 >> 12) ? kg : qg;
      const int row02 = (g2 & (kTilesPerTensor - 1)) * kTileRows;
      #pragma unroll
      for (int it = 0; it < 8; ++it) {
        int f = tid + it * 256;
        int mloc = f >> 5, q4 = f & 31;
        xr[it] = ((const float4*)(Xg2 + (size_t)(row02 + mloc) * kD))[q4];
      }
    }

    lds_barrier();   // B: ldsX(t) fully written

    // ---- compute tile t ----
    bf16x8 xb[4];
    #pragma unroll
    for (int ks = 0; ks < 4; ++ks)
      xb[ks] = *(const bf16x8*)(&ldsX[((w * 4 + ks) * 64 + lane) * 8]);

    // GEMM1 (swapped): Yt[e][m] = sum_d Q[e][d] * X[m][d]
    f32x4 acc[8];
    #pragma unroll
    for (int mt = 0; mt < 8; ++mt) acc[mt] = (f32x4){0.f, 0.f, 0.f, 0.f};
    #pragma unroll
    for (int mt = 0; mt < 8; ++mt) {
      #pragma unroll
      for (int ks = 0; ks < 4; ++ks) {
        bf16x8 a1 = *(const bf16x8*)(&ldsQ[((mt * 4 + ks) * 64 + lane) * 8]);
        acc[mt] = __builtin_amdgcn_mfma_f32_16x16x32_bf16(a1, xb[ks], acc[mt], 0, 0, 0);
      }
    }

    // RoPE in-register: lane holds Yt[e = mt*16+qd*4+reg][m = cc];
    // pair (e, e+64) = (acc[mt], acc[mt+4]); lane's row = row0 + w*16 + cc.
    const float kNegL = -0.20762050593046967f;   // -log2(10000)/64
    {
      float spos = (float)((row0 + w * 16 + cc) & (kS - 1));
      #pragma unroll
      for (int mt = 0; mt < 4; ++mt) {
        #pragma unroll
        for (int reg = 0; reg < 4; ++reg) {
          float fe  = (float)(mt * 16 + qd * 4 + reg);
          float ang = spos * exp2f(kNegL * fe);
          float sv, cv;
          __sincosf(ang, &sv, &cv);
          float ylo = acc[mt][reg];
          float yhi = acc[mt + 4][reg];
          acc[mt][reg]     = ylo * cv - yhi * sv;   // e < 64
          acc[mt + 4][reg] = yhi * cv + ylo * sv;   // e >= 64
        }
      }
    }

    // pack -> in-wave bpermute crossbar -> A-frag(Yrot)
    int pw[16];
    #pragma unroll
    for (int mt = 0; mt < 8; ++mt) {
      #pragma unroll
      for (int p = 0; p < 2; ++p) {
        bf16x2 t;
        t[0] = (__bf16)acc[mt][2 * p];
        t[1] = (__bf16)acc[mt][2 * p + 1];
        pw[mt * 2 + p] = __builtin_bit_cast(int, t);
      }
    }
    bf16x8 a2[4];
    #pragma unroll
    for (int ks = 0; ks < 4; ++ks) {
      i32x4 aw;
      #pragma unroll
      for (int jw = 0; jw < 4; ++jw) {
        int srcl = ((((2 * qd + (jw >> 1)) & 3) * 16) + cc) * 4;
        int wlo = __builtin_amdgcn_ds_bpermute(srcl, pw[4 * ks + (jw & 1)]);
        int whi = __builtin_amdgcn_ds_bpermute(srcl, pw[4 * ks + 2 + (jw & 1)]);
        aw[jw] = (qd < 2) ? wlo : whi;
      }
      a2[ks] = __builtin_bit_cast(bf16x8, aw);
    }

    // GEMM2: Z[m][e'] = sum_e Yrot[m][e] * Q[e][e'] (B wave-uniform from global)
    #pragma unroll
    for (int nt = 0; nt < 8; ++nt) acc[nt] = (f32x4){0.f, 0.f, 0.f, 0.f};
    #pragma unroll
    for (int nt = 0; nt < 8; ++nt) {
      #pragma unroll
      for (int ks = 0; ks < 4; ++ks) {
        bf16x8 b2 = *(const bf16x8*)(wsQf + ((ks * 8 + nt) * 64 + lane) * 8);
        acc[nt] = __builtin_amdgcn_mfma_f32_16x16x32_bf16(a2[ks], b2, acc[nt], 0, 0, 0);
      }
    }

    // direct C-layout stores: 4 rows x 64B contiguous per instruction
    float* __restrict__ Ob = Og + (size_t)(w * 16) * kD;
    #pragma unroll
    for (int nt = 0; nt < 8; ++nt) {
      #pragma unroll
      for (int reg = 0; reg < 4; ++reg)
        Ob[(qd * 4 + reg) * kD + nt * 16 + cc] = acc[nt][reg];
    }
  }
}

extern "C" void kernel_launch(void* const* d_in, const int* in_sizes, int n_in,
                              void* d_out, int out_size, void* d_ws, size_t ws_size,
                              hipStream_t stream) {
  const float* q  = (const float*)d_in[0];
  const float* k  = (const float*)d_in[1];
  const float* vs = (const float*)d_in[2];
  __bf16* wsQA = (__bf16*)d_ws;
  __bf16* wsQf = wsQA + kFragElems;

  rnrope_build_q<<<8, 1024, 0, stream>>>(vs, wsQA, wsQf);
  rnrope_main<<<1024, 256, 0, stream>>>(q, k, wsQA, wsQf, (float*)d_out);
}